// Round 5
// baseline (282.091 us; speedup 1.0000x reference)
//
#include <hip/hip_runtime.h>
#include <math.h>

#define BATCH 64
#define NN 512
#define MM 512
#define DD 128
#define BIGF 1e30f
#define KLOG2E 1.442695040888963f
#define LN2F   0.693147180559945f
#define BIGK   (BIGF * KLOG2E)

// ---------------------------------------------------------------------------
// Kernel 1: squared row norms of X (B*N rows) and Y (B*M rows).
// ---------------------------------------------------------------------------
__global__ __launch_bounds__(256) void sqnorm_kernel(const float* __restrict__ X,
                                                     const float* __restrict__ Y,
                                                     float* __restrict__ x2,
                                                     float* __restrict__ y2) {
    int row  = blockIdx.x * 4 + (threadIdx.x >> 6);
    int lane = threadIdx.x & 63;
    const float* src;
    float* dst;
    int r;
    if (row < BATCH * NN) { src = X; dst = x2; r = row; }
    else                  { src = Y; dst = y2; r = row - BATCH * NN; }
    const float* p = src + (size_t)r * DD;
    float a = p[lane];
    float b = p[lane + 64];
    float s = a * a + b * b;
    #pragma unroll
    for (int m = 32; m >= 1; m >>= 1) s += __shfl_xor(s, m, 64);
    if (lane == 0) dst[r] = s;
}

// ---------------------------------------------------------------------------
// Kernel 2: CT[b,j,i] = (x2[b,i] + y2[b,j] - 2*dot(X,Y)) * (log2e / D)
// Pre-scaled by log2(e) so the DTW kernel works natively in base-2 domain.
// ---------------------------------------------------------------------------
#define TM 64

__global__ __launch_bounds__(256) void cost_kernel(const float* __restrict__ X,
                                                   const float* __restrict__ Y,
                                                   const float* __restrict__ x2,
                                                   const float* __restrict__ y2,
                                                   float* __restrict__ CT) {
    __shared__ float Xs[TM * DD];
    __shared__ float Ys[TM * DD];
    int b  = blockIdx.z;
    int ti = blockIdx.y * TM;
    int tj = blockIdx.x * TM;
    int t  = threadIdx.x;
    const float* Xb = X + ((size_t)b * NN + ti) * DD;
    const float* Yb = Y + ((size_t)b * MM + tj) * DD;

    int k4l = t & 31;
    int rl  = t >> 5;
    #pragma unroll
    for (int it = 0; it < 8; ++it) {
        int r  = rl + it * 8;
        int sw = r * 32 + (k4l ^ ((r >> 2) & 7));
        *(float4*)&Xs[4 * sw] = *(const float4*)&Xb[(size_t)r * DD + 4 * k4l];
        *(float4*)&Ys[4 * sw] = *(const float4*)&Yb[(size_t)r * DD + 4 * k4l];
    }
    __syncthreads();

    int tx = t & 15;
    int ty = t >> 4;
    float acc[4][4] = {};
    #pragma unroll 4
    for (int k4 = 0; k4 < 32; ++k4) {
        float4 xa[4], yb[4];
        int kx = k4 ^ (tx & 7);
        int ky = k4 ^ ty;
        #pragma unroll
        for (int m = 0; m < 4; ++m)
            xa[m] = *(const float4*)&Xs[4 * ((tx * 4 + m) * 32 + kx)];
        #pragma unroll
        for (int n = 0; n < 4; ++n)
            yb[n] = *(const float4*)&Ys[4 * ((ty * 4 + n) * 32 + ky)];
        #pragma unroll
        for (int m = 0; m < 4; ++m)
            #pragma unroll
            for (int n = 0; n < 4; ++n)
                acc[m][n] += xa[m].x * yb[n].x + xa[m].y * yb[n].y
                           + xa[m].z * yb[n].z + xa[m].w * yb[n].w;
    }

    const float inv = KLOG2E / (float)DD;   // base-2 pre-scale
    int i0 = ti + tx * 4;
    float4 xx = *(const float4*)&x2[b * NN + i0];
    #pragma unroll
    for (int n = 0; n < 4; ++n) {
        int j = tj + ty * 4 + n;
        float yy = y2[b * MM + j];
        float4 o;
        o.x = (xx.x + yy - 2.0f * acc[0][n]) * inv;
        o.y = (xx.y + yy - 2.0f * acc[1][n]) * inv;
        o.z = (xx.z + yy - 2.0f * acc[2][n]) * inv;
        o.w = (xx.w + yy - 2.0f * acc[3][n]) * inv;
        *(float4*)&CT[((size_t)b * MM + j) * NN + i0] = o;
    }
}

// ---------------------------------------------------------------------------
// Kernel 3: wave-synchronous soft-DTW, base-2 domain, depth-4 register ring.
// Lane t owns rows [8t,8t+8); computes column j = s - t at step s.
// Loads are UNCONDITIONAL with &511-clamped column (always in the batch's
// 1MB slice; garbage columns never consumed) so the compiler can keep the
// depth-4 pipeline live. Trip count 576 = 4*144 so `#pragma unroll 4` has no
// remainder loop (ring indices stay compile-time -> registers, not scratch).
// Cell (0,0) handled by seeding lane0's ud=0 at s=0: formula yields exactly c.
// ---------------------------------------------------------------------------
__global__ __launch_bounds__(64) void sdtw_kernel(const float* __restrict__ CT,
                                                  float* __restrict__ part) {
    int b = blockIdx.x;
    int t = threadIdx.x;
    const char* Cb = (const char*)(CT + (size_t)b * MM * NN);   // CT[j][i]
    int r0 = t * 8;
    int rb = r0 << 2;              // byte offset of row block within a column

    float prev[8];
    #pragma unroll
    for (int r = 0; r < 8; ++r) prev[r] = BIGK;
    float nb_cur = BIGK, nb_prev = BIGK;

    float4 bufA[4], bufB[4];
    #pragma unroll
    for (int p = 0; p < 4; ++p) {   // columns (p - t) & 511
        int jc  = (p - t) & 511;
        int off = (jc << 11) + rb;
        bufA[p] = *(const float4*)(Cb + off);
        bufB[p] = *(const float4*)(Cb + off + 16);
    }

    #pragma unroll 4
    for (int s = 0; s < 576; ++s) {
        int j = s - t;
        float4 cA = bufA[s & 3], cB = bufB[s & 3];
        {   // issue load for step s+4 into the slot just consumed
            int jc  = (j + 4) & 511;
            int off = (jc << 11) + rb;
            bufA[s & 3] = *(const float4*)(Cb + off);
            bufB[s & 3] = *(const float4*)(Cb + off + 16);
        }
        if (j >= 0 && j < MM) {
            float cc[8] = {cA.x, cA.y, cA.z, cA.w, cB.x, cB.y, cB.z, cB.w};
            float t0ud = (s == 0) ? 0.0f : BIGK;          // seeds cell (0,0)
            float up = (t == 0) ? BIGK  : nb_cur;         // (r0-1, j)
            float ud = (t == 0) ? t0ud  : nb_prev;        // (r0-1, j-1)
            #pragma unroll
            for (int r = 0; r < 8; ++r) {
                float left = prev[r];                     // (r0+r, j-1)
                float mn;
                asm("v_min3_f32 %0, %1, %2, %3" : "=v"(mn) : "v"(up), "v"(left), "v"(ud));
                float ckmn = cc[r] + mn;                  // off critical chain
                float d0 = mn - up, d1 = mn - left, d2 = mn - ud;
                float e0, e1, e2;
                asm("v_exp_f32 %0, %1" : "=v"(e0) : "v"(d0));
                asm("v_exp_f32 %0, %1" : "=v"(e1) : "v"(d1));
                asm("v_exp_f32 %0, %1" : "=v"(e2) : "v"(d2));
                float sum = (e0 + e1) + e2;
                float lg;
                asm("v_log_f32 %0, %1" : "=v"(lg) : "v"(sum));
                float v = ckmn - lg;
                prev[r] = v;
                ud = left;
                up = v;
            }
        }
        float sh = __shfl_up(prev[7], 1);
        nb_prev = nb_cur;
        nb_cur = sh;
    }
    if (t == 63) part[b] = prev[7] * LN2F;   // cell (511,511), back to nats
}

// ---------------------------------------------------------------------------
// Kernel 4: deterministic reduction. out = sum_b(R_b) / (B * N)
// ---------------------------------------------------------------------------
__global__ void reduce_kernel(const float* __restrict__ part, float* __restrict__ out) {
    if (threadIdx.x == 0) {
        float s = 0.0f;
        for (int b2 = 0; b2 < BATCH; ++b2) s += part[b2];
        out[0] = s / (float)(BATCH * NN);
    }
}

// ---------------------------------------------------------------------------
extern "C" void kernel_launch(void* const* d_in, const int* in_sizes, int n_in,
                              void* d_out, int out_size, void* d_ws, size_t ws_size,
                              hipStream_t stream) {
    const float* X = (const float*)d_in[0];
    const float* Y = (const float*)d_in[1];
    float* out = (float*)d_out;

    char* ws = (char*)d_ws;
    float* CT   = (float*)ws;                                   // 64 MB
    float* x2   = (float*)(ws + (size_t)BATCH * NN * MM * 4);   // 128 KB
    float* y2   = x2 + BATCH * NN;                              // 128 KB
    float* part = y2 + BATCH * MM;                              // 256 B

    sqnorm_kernel<<<(BATCH * (NN + MM)) / 4, 256, 0, stream>>>(X, Y, x2, y2);

    dim3 g(MM / TM, NN / TM, BATCH);
    cost_kernel<<<g, 256, 0, stream>>>(X, Y, x2, y2, CT);

    sdtw_kernel<<<BATCH, 64, 0, stream>>>(CT, part);

    reduce_kernel<<<1, 64, 0, stream>>>(part, out);
}

// Round 6
// 260.582 us; speedup vs baseline: 1.0825x; 1.0825x over previous
//
#include <hip/hip_runtime.h>
#include <math.h>

#define BATCH 64
#define NN 512
#define MM 512
#define DD 128
#define BIGF 1e30f
#define KLOG2E 1.442695040888963f
#define LN2F   0.693147180559945f
#define BIGK   (BIGF * KLOG2E)

typedef __attribute__((ext_vector_type(4))) float f32x4;

// ---------------------------------------------------------------------------
// Kernel 1: squared row norms of X (B*N rows) and Y (B*M rows).
// ---------------------------------------------------------------------------
__global__ __launch_bounds__(256) void sqnorm_kernel(const float* __restrict__ X,
                                                     const float* __restrict__ Y,
                                                     float* __restrict__ x2,
                                                     float* __restrict__ y2) {
    int row  = blockIdx.x * 4 + (threadIdx.x >> 6);
    int lane = threadIdx.x & 63;
    const float* src;
    float* dst;
    int r;
    if (row < BATCH * NN) { src = X; dst = x2; r = row; }
    else                  { src = Y; dst = y2; r = row - BATCH * NN; }
    const float* p = src + (size_t)r * DD;
    float a = p[lane];
    float b = p[lane + 64];
    float s = a * a + b * b;
    #pragma unroll
    for (int m = 32; m >= 1; m >>= 1) s += __shfl_xor(s, m, 64);
    if (lane == 0) dst[r] = s;
}

// ---------------------------------------------------------------------------
// Kernel 2: CT[b,j,i] = (x2[b,i] + y2[b,j] - 2*dot(X,Y)) * (log2e / D)
// Pre-scaled by log2(e): DTW kernel runs natively in base-2 domain.
// ---------------------------------------------------------------------------
#define TM 64

__global__ __launch_bounds__(256) void cost_kernel(const float* __restrict__ X,
                                                   const float* __restrict__ Y,
                                                   const float* __restrict__ x2,
                                                   const float* __restrict__ y2,
                                                   float* __restrict__ CT) {
    __shared__ float Xs[TM * DD];
    __shared__ float Ys[TM * DD];
    int b  = blockIdx.z;
    int ti = blockIdx.y * TM;
    int tj = blockIdx.x * TM;
    int t  = threadIdx.x;
    const float* Xb = X + ((size_t)b * NN + ti) * DD;
    const float* Yb = Y + ((size_t)b * MM + tj) * DD;

    int k4l = t & 31;
    int rl  = t >> 5;
    #pragma unroll
    for (int it = 0; it < 8; ++it) {
        int r  = rl + it * 8;
        int sw = r * 32 + (k4l ^ ((r >> 2) & 7));
        *(float4*)&Xs[4 * sw] = *(const float4*)&Xb[(size_t)r * DD + 4 * k4l];
        *(float4*)&Ys[4 * sw] = *(const float4*)&Yb[(size_t)r * DD + 4 * k4l];
    }
    __syncthreads();

    int tx = t & 15;
    int ty = t >> 4;
    float acc[4][4] = {};
    #pragma unroll 4
    for (int k4 = 0; k4 < 32; ++k4) {
        float4 xa[4], yb[4];
        int kx = k4 ^ (tx & 7);
        int ky = k4 ^ ty;
        #pragma unroll
        for (int m = 0; m < 4; ++m)
            xa[m] = *(const float4*)&Xs[4 * ((tx * 4 + m) * 32 + kx)];
        #pragma unroll
        for (int n = 0; n < 4; ++n)
            yb[n] = *(const float4*)&Ys[4 * ((ty * 4 + n) * 32 + ky)];
        #pragma unroll
        for (int m = 0; m < 4; ++m)
            #pragma unroll
            for (int n = 0; n < 4; ++n)
                acc[m][n] += xa[m].x * yb[n].x + xa[m].y * yb[n].y
                           + xa[m].z * yb[n].z + xa[m].w * yb[n].w;
    }

    const float inv = KLOG2E / (float)DD;
    int i0 = ti + tx * 4;
    float4 xx = *(const float4*)&x2[b * NN + i0];
    #pragma unroll
    for (int n = 0; n < 4; ++n) {
        int j = tj + ty * 4 + n;
        float yy = y2[b * MM + j];
        float4 o;
        o.x = (xx.x + yy - 2.0f * acc[0][n]) * inv;
        o.y = (xx.y + yy - 2.0f * acc[1][n]) * inv;
        o.z = (xx.z + yy - 2.0f * acc[2][n]) * inv;
        o.w = (xx.w + yy - 2.0f * acc[3][n]) * inv;
        *(float4*)&CT[((size_t)b * MM + j) * NN + i0] = o;
    }
}

// ---------------------------------------------------------------------------
// Kernel 3: wave-synchronous soft-DTW, base-2 domain, INLINE-ASM depth-6 ring.
// Lane t owns rows [8t,8t+8); computes column j = s - t at step s (576 steps,
// 576 = 6*96 so ring slots are compile-time names a0..b5). All global loads
// are asm volatile global_load_dwordx4 (compiler inserts NO waits for them);
// one manual s_waitcnt vmcnt(10) + sched_barrier(0) per step retires exactly
// the slot being consumed while 10 loads (5 steps) stay in flight.
// Softmin (3-trans form): one of {up,left,ud} IS the min, so
//   v = c + mn - log2(1 + 2^(mn-med3) + 2^(mn-max3)).
// Cell (0,0): lane0 ud seeded 0 at s=0 -> formula yields exactly c.
// ---------------------------------------------------------------------------
#define RING 6

__global__ __launch_bounds__(64) void sdtw_kernel(const float* __restrict__ CT,
                                                  float* __restrict__ part) {
    int b = blockIdx.x;
    int t = threadIdx.x;
    const char* CbL = (const char*)CT + (size_t)b * (MM * NN * 4) + t * 32;

    float prev[8];
    #pragma unroll
    for (int r = 0; r < 8; ++r) prev[r] = BIGK;
    float nb_cur = BIGK, nb_prev = BIGK;

    f32x4 a0, b0, a1, b1, a2, b2, a3, b3, a4, b4, a5, b5;

#define LOADPAIR(AP, BP, COL) do {                                             \
    const char* pa_ = CbL + (((unsigned)(COL)) & 511u) * 2048u;                \
    asm volatile("global_load_dwordx4 %0, %2, off\n\t"                         \
                 "global_load_dwordx4 %1, %2, off offset:16"                   \
                 : "=&v"(AP), "=&v"(BP) : "v"(pa_) : "memory");                \
} while (0)

    // prologue: slots 0..5 hold steps 0..5 (columns p - t, wrapped)
    LOADPAIR(a0, b0, 0 - t);
    LOADPAIR(a1, b1, 1 - t);
    LOADPAIR(a2, b2, 2 - t);
    LOADPAIR(a3, b3, 3 - t);
    LOADPAIR(a4, b4, 4 - t);
    LOADPAIR(a5, b5, 5 - t);

#define STEP(AP, BP, S) do {                                                   \
    int s_ = (S);                                                              \
    int j_ = s_ - t;                                                           \
    asm volatile("s_waitcnt vmcnt(10)" ::: "memory");                          \
    __builtin_amdgcn_sched_barrier(0);                                         \
    f32x4 cA = AP, cB = BP;                                                    \
    if ((unsigned)j_ < 512u) {                                                 \
        float cc[8] = {cA[0], cA[1], cA[2], cA[3], cB[0], cB[1], cB[2], cB[3]};\
        float up = (t == 0) ? BIGK : nb_cur;                                   \
        float ud = (t == 0) ? ((s_ == 0) ? 0.0f : BIGK) : nb_prev;             \
        _Pragma("unroll")                                                      \
        for (int r = 0; r < 8; ++r) {                                          \
            float left = prev[r];                                              \
            float mn, mx, md;                                                  \
            asm("v_min3_f32 %0, %1, %2, %3" : "=v"(mn) : "v"(up), "v"(left), "v"(ud)); \
            asm("v_max3_f32 %0, %1, %2, %3" : "=v"(mx) : "v"(up), "v"(left), "v"(ud)); \
            asm("v_med3_f32 %0, %1, %2, %3" : "=v"(md) : "v"(up), "v"(left), "v"(ud)); \
            float dm = mn - md, dx = mn - mx;                                  \
            float em, ex;                                                      \
            asm("v_exp_f32 %0, %1" : "=v"(em) : "v"(dm));                      \
            asm("v_exp_f32 %0, %1" : "=v"(ex) : "v"(dx));                      \
            float sum = (em + ex) + 1.0f;                                      \
            float lg;                                                          \
            asm("v_log_f32 %0, %1" : "=v"(lg) : "v"(sum));                     \
            float v = (cc[r] + mn) - lg;                                       \
            prev[r] = v;                                                       \
            ud = left;                                                         \
            up = v;                                                            \
        }                                                                      \
    }                                                                          \
    LOADPAIR(AP, BP, s_ + RING - t);                                           \
    float sh_ = __shfl_up(prev[7], 1);                                         \
    nb_prev = nb_cur;                                                          \
    nb_cur = sh_;                                                              \
} while (0)

    for (int it = 0; it < 96; ++it) {
        int s0 = it * 6;
        STEP(a0, b0, s0 + 0);
        STEP(a1, b1, s0 + 1);
        STEP(a2, b2, s0 + 2);
        STEP(a3, b3, s0 + 3);
        STEP(a4, b4, s0 + 4);
        STEP(a5, b5, s0 + 5);
    }

    if (t == 63) part[b] = prev[7] * LN2F;   // cell (511,511), back to nats
#undef STEP
#undef LOADPAIR
}

// ---------------------------------------------------------------------------
// Kernel 4: one-wave deterministic reduction. out = sum_b(R_b) / (B * N)
// ---------------------------------------------------------------------------
__global__ __launch_bounds__(64) void reduce_kernel(const float* __restrict__ part,
                                                    float* __restrict__ out) {
    int l = threadIdx.x;
    float v = part[l];
    #pragma unroll
    for (int m = 32; m >= 1; m >>= 1) v += __shfl_xor(v, m, 64);
    if (l == 0) out[0] = v / (float)(BATCH * NN);
}

// ---------------------------------------------------------------------------
extern "C" void kernel_launch(void* const* d_in, const int* in_sizes, int n_in,
                              void* d_out, int out_size, void* d_ws, size_t ws_size,
                              hipStream_t stream) {
    const float* X = (const float*)d_in[0];
    const float* Y = (const float*)d_in[1];
    float* out = (float*)d_out;

    char* ws = (char*)d_ws;
    float* CT   = (float*)ws;                                   // 64 MB
    float* x2   = (float*)(ws + (size_t)BATCH * NN * MM * 4);   // 128 KB
    float* y2   = x2 + BATCH * NN;                              // 128 KB
    float* part = y2 + BATCH * MM;                              // 256 B

    sqnorm_kernel<<<(BATCH * (NN + MM)) / 4, 256, 0, stream>>>(X, Y, x2, y2);

    dim3 g(MM / TM, NN / TM, BATCH);
    cost_kernel<<<g, 256, 0, stream>>>(X, Y, x2, y2, CT);

    sdtw_kernel<<<BATCH, 64, 0, stream>>>(CT, part);

    reduce_kernel<<<1, 64, 0, stream>>>(part, out);
}

// Round 7
// 245.944 us; speedup vs baseline: 1.1470x; 1.0595x over previous
//
#include <hip/hip_runtime.h>
#include <math.h>

#define BATCH 64
#define NN 512
#define MM 512
#define DD 128
#define BIGF 1e30f
#define KLOG2E 1.442695040888963f
#define LN2F   0.693147180559945f
#define BIGK   (BIGF * KLOG2E)

typedef __attribute__((ext_vector_type(4))) float f32x4;

// ---------------------------------------------------------------------------
// Kernel 1: squared row norms of X (B*N rows) and Y (B*M rows).
// ---------------------------------------------------------------------------
__global__ __launch_bounds__(256) void sqnorm_kernel(const float* __restrict__ X,
                                                     const float* __restrict__ Y,
                                                     float* __restrict__ x2,
                                                     float* __restrict__ y2) {
    int row  = blockIdx.x * 4 + (threadIdx.x >> 6);
    int lane = threadIdx.x & 63;
    const float* src;
    float* dst;
    int r;
    if (row < BATCH * NN) { src = X; dst = x2; r = row; }
    else                  { src = Y; dst = y2; r = row - BATCH * NN; }
    const float* p = src + (size_t)r * DD;
    float a = p[lane];
    float b = p[lane + 64];
    float s = a * a + b * b;
    #pragma unroll
    for (int m = 32; m >= 1; m >>= 1) s += __shfl_xor(s, m, 64);
    if (lane == 0) dst[r] = s;
}

// ---------------------------------------------------------------------------
// Kernel 2: CT[b,j,i] = (x2[b,i] + y2[b,j] - 2*dot(X,Y)) * (log2e / D)
// Pre-scaled by log2(e): DTW kernel runs natively in base-2 domain.
// ---------------------------------------------------------------------------
#define TM 64

__global__ __launch_bounds__(256) void cost_kernel(const float* __restrict__ X,
                                                   const float* __restrict__ Y,
                                                   const float* __restrict__ x2,
                                                   const float* __restrict__ y2,
                                                   float* __restrict__ CT) {
    __shared__ float Xs[TM * DD];
    __shared__ float Ys[TM * DD];
    int b  = blockIdx.z;
    int ti = blockIdx.y * TM;
    int tj = blockIdx.x * TM;
    int t  = threadIdx.x;
    const float* Xb = X + ((size_t)b * NN + ti) * DD;
    const float* Yb = Y + ((size_t)b * MM + tj) * DD;

    int k4l = t & 31;
    int rl  = t >> 5;
    #pragma unroll
    for (int it = 0; it < 8; ++it) {
        int r  = rl + it * 8;
        int sw = r * 32 + (k4l ^ ((r >> 2) & 7));
        *(float4*)&Xs[4 * sw] = *(const float4*)&Xb[(size_t)r * DD + 4 * k4l];
        *(float4*)&Ys[4 * sw] = *(const float4*)&Yb[(size_t)r * DD + 4 * k4l];
    }
    __syncthreads();

    int tx = t & 15;
    int ty = t >> 4;
    float acc[4][4] = {};
    #pragma unroll 4
    for (int k4 = 0; k4 < 32; ++k4) {
        float4 xa[4], yb[4];
        int kx = k4 ^ (tx & 7);
        int ky = k4 ^ ty;
        #pragma unroll
        for (int m = 0; m < 4; ++m)
            xa[m] = *(const float4*)&Xs[4 * ((tx * 4 + m) * 32 + kx)];
        #pragma unroll
        for (int n = 0; n < 4; ++n)
            yb[n] = *(const float4*)&Ys[4 * ((ty * 4 + n) * 32 + ky)];
        #pragma unroll
        for (int m = 0; m < 4; ++m)
            #pragma unroll
            for (int n = 0; n < 4; ++n)
                acc[m][n] += xa[m].x * yb[n].x + xa[m].y * yb[n].y
                           + xa[m].z * yb[n].z + xa[m].w * yb[n].w;
    }

    const float inv = KLOG2E / (float)DD;
    int i0 = ti + tx * 4;
    float4 xx = *(const float4*)&x2[b * NN + i0];
    #pragma unroll
    for (int n = 0; n < 4; ++n) {
        int j = tj + ty * 4 + n;
        float yy = y2[b * MM + j];
        float4 o;
        o.x = (xx.x + yy - 2.0f * acc[0][n]) * inv;
        o.y = (xx.y + yy - 2.0f * acc[1][n]) * inv;
        o.z = (xx.z + yy - 2.0f * acc[2][n]) * inv;
        o.w = (xx.w + yy - 2.0f * acc[3][n]) * inv;
        *(float4*)&CT[((size_t)b * MM + j) * NN + i0] = o;
    }
}

// ---------------------------------------------------------------------------
// Kernel 3: wave-synchronous soft-DTW, scale+mass (s,q) form, asm load ring.
// Cell value carried as v = s - log2(q). softmin is scale-invariant, so the
// scale recursion is pure min+add (8 cyc/cell serial chain):
//     m   = min(s_up, min(left, ud))        [left, ud resolved, off-chain]
//     s_r = c_r + m
//     q_r = fma(q_up, 2^(m-s_up), 2^(m-left) + 2^(m-ud))   [exps off s-chain]
//     prev[r] = s_r - log2(q_r)             [resolve: needed next step only]
// All exponents <= 0 by construction (m = min3 incl. left, ud) -> no overflow;
// per-cell resolve caps q growth; BIG boundaries absorb via 2^(-huge) = 0.
// Handoff: shfl the (s7,q7) pair; diagonal input consumed as a pair too.
// Cell (0,0): lane0 step0 ud-pair = (0,1) -> v = c exactly.
// ---------------------------------------------------------------------------
#define RING 6

__global__ __launch_bounds__(64) void sdtw_kernel(const float* __restrict__ CT,
                                                  float* __restrict__ part) {
    int b = blockIdx.x;
    int t = threadIdx.x;
    const char* CbL = (const char*)CT + (size_t)b * (MM * NN * 4) + t * 32;

    float prev[8];
    #pragma unroll
    for (int r = 0; r < 8; ++r) prev[r] = BIGK;
    float nbc_s = BIGK, nbc_q = 1.0f;   // up pair (neighbor bottom, col j)
    float nbp_s = BIGK, nbp_q = 1.0f;   // diag pair (neighbor bottom, col j-1)
    float sBot = BIGK, qBot = 1.0f;

    f32x4 a0, b0, a1, b1, a2, b2, a3, b3, a4, b4, a5, b5;

#define LOADPAIR(AP, BP, COL) do {                                             \
    const char* pa_ = CbL + (((unsigned)(COL)) & 511u) * 2048u;                \
    asm volatile("global_load_dwordx4 %0, %2, off\n\t"                         \
                 "global_load_dwordx4 %1, %2, off offset:16"                   \
                 : "=&v"(AP), "=&v"(BP) : "v"(pa_) : "memory");                \
} while (0)

    LOADPAIR(a0, b0, 0 - t);
    LOADPAIR(a1, b1, 1 - t);
    LOADPAIR(a2, b2, 2 - t);
    LOADPAIR(a3, b3, 3 - t);
    LOADPAIR(a4, b4, 4 - t);
    LOADPAIR(a5, b5, 5 - t);

#define STEP(AP, BP, S) do {                                                   \
    int s_ = (S);                                                              \
    int j_ = s_ - t;                                                           \
    asm volatile("s_waitcnt vmcnt(10)" ::: "memory");                          \
    __builtin_amdgcn_sched_barrier(0);                                         \
    f32x4 cA = AP, cB = BP;                                                    \
    if ((unsigned)j_ < 512u) {                                                 \
        float cc[8] = {cA[0],cA[1],cA[2],cA[3],cB[0],cB[1],cB[2],cB[3]};       \
        float us  = (t == 0) ? BIGK : nbc_s;                                   \
        float ds_ = (t == 0) ? ((s_ == 0) ? 0.0f : BIGK) : nbp_s;              \
        /* cell 0: up and diag are carried (s,q) pairs */                      \
        float left = prev[0];                                                  \
        float pre  = fminf(left, ds_);                                         \
        float m    = fminf(us, pre);                                           \
        float Eu, El, Ed;                                                      \
        asm("v_exp_f32 %0, %1" : "=v"(Eu) : "v"(m - us));                      \
        asm("v_exp_f32 %0, %1" : "=v"(El) : "v"(m - left));                    \
        asm("v_exp_f32 %0, %1" : "=v"(Ed) : "v"(m - ds_));                     \
        float qC = __builtin_fmaf(nbc_q, Eu, __builtin_fmaf(nbp_q, Ed, El));   \
        float sC = cc[0] + m;                                                  \
        float lg0;                                                             \
        asm("v_log_f32 %0, %1" : "=v"(lg0) : "v"(qC));                         \
        float ud_res = left;                                                   \
        prev[0] = sC - lg0;                                                    \
        _Pragma("unroll")                                                      \
        for (int r = 1; r < 8; ++r) {                                          \
            float lf = prev[r];                                                \
            float pr = fminf(lf, ud_res);                                      \
            float mm = fminf(sC, pr);                                          \
            float eu, el, ed;                                                  \
            asm("v_exp_f32 %0, %1" : "=v"(eu) : "v"(mm - sC));                 \
            asm("v_exp_f32 %0, %1" : "=v"(el) : "v"(mm - lf));                 \
            asm("v_exp_f32 %0, %1" : "=v"(ed) : "v"(mm - ud_res));             \
            float qn = __builtin_fmaf(qC, eu, el + ed);                        \
            float sn = cc[r] + mm;                                             \
            float lgr;                                                         \
            asm("v_log_f32 %0, %1" : "=v"(lgr) : "v"(qn));                     \
            prev[r] = sn - lgr;                                                \
            ud_res = lf;                                                       \
            sC = sn; qC = qn;                                                  \
        }                                                                      \
        sBot = sC; qBot = qC;                                                  \
    }                                                                          \
    LOADPAIR(AP, BP, s_ + RING - t);                                           \
    float shs_ = __shfl_up(sBot, 1);                                           \
    float shq_ = __shfl_up(qBot, 1);                                           \
    nbp_s = nbc_s; nbp_q = nbc_q;                                              \
    nbc_s = shs_; nbc_q = shq_;                                                \
} while (0)

    for (int it = 0; it < 96; ++it) {
        int s0 = it * 6;
        STEP(a0, b0, s0 + 0);
        STEP(a1, b1, s0 + 1);
        STEP(a2, b2, s0 + 2);
        STEP(a3, b3, s0 + 3);
        STEP(a4, b4, s0 + 4);
        STEP(a5, b5, s0 + 5);
    }

    if (t == 63) part[b] = prev[7] * LN2F;   // cell (511,511), back to nats
#undef STEP
#undef LOADPAIR
}

// ---------------------------------------------------------------------------
// Kernel 4: one-wave deterministic reduction. out = sum_b(R_b) / (B * N)
// ---------------------------------------------------------------------------
__global__ __launch_bounds__(64) void reduce_kernel(const float* __restrict__ part,
                                                    float* __restrict__ out) {
    int l = threadIdx.x;
    float v = part[l];
    #pragma unroll
    for (int m = 32; m >= 1; m >>= 1) v += __shfl_xor(v, m, 64);
    if (l == 0) out[0] = v / (float)(BATCH * NN);
}

// ---------------------------------------------------------------------------
extern "C" void kernel_launch(void* const* d_in, const int* in_sizes, int n_in,
                              void* d_out, int out_size, void* d_ws, size_t ws_size,
                              hipStream_t stream) {
    const float* X = (const float*)d_in[0];
    const float* Y = (const float*)d_in[1];
    float* out = (float*)d_out;

    char* ws = (char*)d_ws;
    float* CT   = (float*)ws;                                   // 64 MB
    float* x2   = (float*)(ws + (size_t)BATCH * NN * MM * 4);   // 128 KB
    float* y2   = x2 + BATCH * NN;                              // 128 KB
    float* part = y2 + BATCH * MM;                              // 256 B

    sqnorm_kernel<<<(BATCH * (NN + MM)) / 4, 256, 0, stream>>>(X, Y, x2, y2);

    dim3 g(MM / TM, NN / TM, BATCH);
    cost_kernel<<<g, 256, 0, stream>>>(X, Y, x2, y2, CT);

    sdtw_kernel<<<BATCH, 64, 0, stream>>>(CT, part);

    reduce_kernel<<<1, 64, 0, stream>>>(part, out);
}

// Round 8
// 245.709 us; speedup vs baseline: 1.1481x; 1.0010x over previous
//
#include <hip/hip_runtime.h>
#include <math.h>

#define BATCH 64
#define NN 512
#define MM 512
#define DD 128
#define BIGF 1e30f
#define KLOG2E 1.442695040888963f
#define LN2F   0.693147180559945f
#define BIGK   (BIGF * KLOG2E)

typedef __attribute__((ext_vector_type(2))) float f32x2;

// ---------------------------------------------------------------------------
// Kernel 1: squared row norms of X (B*N rows) and Y (B*M rows).
// ---------------------------------------------------------------------------
__global__ __launch_bounds__(256) void sqnorm_kernel(const float* __restrict__ X,
                                                     const float* __restrict__ Y,
                                                     float* __restrict__ x2,
                                                     float* __restrict__ y2) {
    int row  = blockIdx.x * 4 + (threadIdx.x >> 6);
    int lane = threadIdx.x & 63;
    const float* src;
    float* dst;
    int r;
    if (row < BATCH * NN) { src = X; dst = x2; r = row; }
    else                  { src = Y; dst = y2; r = row - BATCH * NN; }
    const float* p = src + (size_t)r * DD;
    float a = p[lane];
    float b = p[lane + 64];
    float s = a * a + b * b;
    #pragma unroll
    for (int m = 32; m >= 1; m >>= 1) s += __shfl_xor(s, m, 64);
    if (lane == 0) dst[r] = s;
}

// ---------------------------------------------------------------------------
// Kernel 2: CT[b,j,i] = (x2[b,i] + y2[b,j] - 2*dot(X,Y)) * (log2e / D)
// Pre-scaled by log2(e): DTW kernel runs natively in base-2 domain.
// ---------------------------------------------------------------------------
#define TM 64

__global__ __launch_bounds__(256) void cost_kernel(const float* __restrict__ X,
                                                   const float* __restrict__ Y,
                                                   const float* __restrict__ x2,
                                                   const float* __restrict__ y2,
                                                   float* __restrict__ CT) {
    __shared__ float Xs[TM * DD];
    __shared__ float Ys[TM * DD];
    int b  = blockIdx.z;
    int ti = blockIdx.y * TM;
    int tj = blockIdx.x * TM;
    int t  = threadIdx.x;
    const float* Xb = X + ((size_t)b * NN + ti) * DD;
    const float* Yb = Y + ((size_t)b * MM + tj) * DD;

    int k4l = t & 31;
    int rl  = t >> 5;
    #pragma unroll
    for (int it = 0; it < 8; ++it) {
        int r  = rl + it * 8;
        int sw = r * 32 + (k4l ^ ((r >> 2) & 7));
        *(float4*)&Xs[4 * sw] = *(const float4*)&Xb[(size_t)r * DD + 4 * k4l];
        *(float4*)&Ys[4 * sw] = *(const float4*)&Yb[(size_t)r * DD + 4 * k4l];
    }
    __syncthreads();

    int tx = t & 15;
    int ty = t >> 4;
    float acc[4][4] = {};
    #pragma unroll 4
    for (int k4 = 0; k4 < 32; ++k4) {
        float4 xa[4], yb[4];
        int kx = k4 ^ (tx & 7);
        int ky = k4 ^ ty;
        #pragma unroll
        for (int m = 0; m < 4; ++m)
            xa[m] = *(const float4*)&Xs[4 * ((tx * 4 + m) * 32 + kx)];
        #pragma unroll
        for (int n = 0; n < 4; ++n)
            yb[n] = *(const float4*)&Ys[4 * ((ty * 4 + n) * 32 + ky)];
        #pragma unroll
        for (int m = 0; m < 4; ++m)
            #pragma unroll
            for (int n = 0; n < 4; ++n)
                acc[m][n] += xa[m].x * yb[n].x + xa[m].y * yb[n].y
                           + xa[m].z * yb[n].z + xa[m].w * yb[n].w;
    }

    const float inv = KLOG2E / (float)DD;
    int i0 = ti + tx * 4;
    float4 xx = *(const float4*)&x2[b * NN + i0];
    #pragma unroll
    for (int n = 0; n < 4; ++n) {
        int j = tj + ty * 4 + n;
        float yy = y2[b * MM + j];
        float4 o;
        o.x = (xx.x + yy - 2.0f * acc[0][n]) * inv;
        o.y = (xx.y + yy - 2.0f * acc[1][n]) * inv;
        o.z = (xx.z + yy - 2.0f * acc[2][n]) * inv;
        o.w = (xx.w + yy - 2.0f * acc[3][n]) * inv;
        *(float4*)&CT[((size_t)b * MM + j) * NN + i0] = o;
    }
}

// ---------------------------------------------------------------------------
// Kernel 3: 4-wave soft-DTW, log-free (s,q) carry, asm load ring, raw barrier.
// 256 threads/block, one block per batch. Thread p owns rows 2p..2p+1 and
// computes column j = s - p at step s (768 steps). Cell value carried as an
// UNRESOLVED pair v = s - log2(q):
//   m  = min3(s_up, s_left, s_diag)            (scales; m - s_i <= 0 always)
//   q' = q_up*2^(m-s_up) + q_left*2^(m-s_left) + q_diag*2^(m-s_diag)
//   s' = c + m
// -> 3 exps, NO log per cell (single log at the very end). q >= 1 inductively
// (argmin term has coeff 1); grows <=3x/cell -> renorm every 6 steps by
// exponent bit-extraction (int ops). In-wave handoff: shfl the bottom pair.
// Cross-wave handoff (lane 0): depth-3 LDS ring of lane-63 bottom pairs, one
// RAW s_barrier + lgkmcnt(0) per step (no vmcnt drain -> load ring survives).
// Global loads: asm depth-6 ring, vmcnt(5), flight = 6 steps >> HBM latency.
// Cell (0,0): wave0/lane0/s0 diag pair seeded (0,1) -> v = c exactly.
// ---------------------------------------------------------------------------
#define RING 6

__global__ __launch_bounds__(256) void sdtw_kernel(const float* __restrict__ CT,
                                                   float* __restrict__ part) {
    int b = blockIdx.x;
    int p = threadIdx.x;          // 0..255
    int l = p & 63;
    int w = p >> 6;
    int wm1 = (w == 0) ? 0 : (w - 1);
    const char* CbL = (const char*)CT + (size_t)b * (MM * NN * 4) + p * 8; // rows 2p,2p+1

    __shared__ f32x2 bsq[3][4];   // [step%3][wave] lane-63 bottom (s,q)

    if (p < 12) bsq[p >> 2][p & 3] = f32x2{BIGK, 1.0f};
    __syncthreads();

    float ps0 = BIGK, pq0 = 1.0f;   // row 2p   (s,q) at column j-1
    float ps1 = BIGK, pq1 = 1.0f;   // row 2p+1 (s,q) at column j-1
    float nbc_s = BIGK, nbc_q = 1.0f;  // neighbor bottom @ col j   (up of A)
    float nbp_s = BIGK, nbp_q = 1.0f;  // neighbor bottom @ col j-1 (diag of A)

    f32x2 r0, r1, r2, r3, r4, r5;

#define LOADP(REG, COL) do {                                                   \
    const char* pa_ = CbL + (((unsigned)(COL)) & 511u) * 2048u;                \
    asm volatile("global_load_dwordx2 %0, %1, off"                             \
                 : "=&v"(REG) : "v"(pa_) : "memory");                          \
} while (0)

    LOADP(r0, 0 - p); LOADP(r1, 1 - p); LOADP(r2, 2 - p);
    LOADP(r3, 3 - p); LOADP(r4, 4 - p); LOADP(r5, 5 - p);

#define STEP(REG, S, SW, SU, SD) do {                                          \
    int s_ = (S);                                                              \
    int j_ = s_ - p;                                                           \
    asm volatile("s_waitcnt lgkmcnt(0)" ::: "memory");                         \
    __builtin_amdgcn_s_barrier();                                              \
    asm volatile("" ::: "memory");                                             \
    f32x2 ubot = bsq[SU][wm1];   /* wave w-1 bottom @ step s-1 */              \
    f32x2 dbot = bsq[SD][wm1];   /* wave w-1 bottom @ step s-2 */              \
    asm volatile("s_waitcnt vmcnt(5)" ::: "memory");                           \
    __builtin_amdgcn_sched_barrier(0);                                         \
    f32x2 cc = REG;                                                            \
    float su, qu, sd2, qd;                                                     \
    if (l == 0) {                                                              \
        if (w == 0) { su = BIGK; qu = 1.0f;                                    \
                      sd2 = (s_ == 0) ? 0.0f : BIGK; qd = 1.0f; }              \
        else        { su = ubot.x; qu = ubot.y; sd2 = dbot.x; qd = dbot.y; }   \
    } else { su = nbc_s; qu = nbc_q; sd2 = nbp_s; qd = nbp_q; }                \
    if ((unsigned)j_ < 512u) {                                                 \
        float lAs = ps0, lAq = pq0;                                            \
        float m1;                                                              \
        asm("v_min3_f32 %0, %1, %2, %3" : "=v"(m1) : "v"(su), "v"(lAs), "v"(sd2)); \
        float eu, el, ed;                                                      \
        asm("v_exp_f32 %0, %1" : "=v"(eu) : "v"(m1 - su));                     \
        asm("v_exp_f32 %0, %1" : "=v"(el) : "v"(m1 - lAs));                    \
        asm("v_exp_f32 %0, %1" : "=v"(ed) : "v"(m1 - sd2));                    \
        float qA = __builtin_fmaf(qu, eu, __builtin_fmaf(lAq, el, qd * ed));   \
        float sA = cc.x + m1;                                                  \
        float m2;                                                              \
        asm("v_min3_f32 %0, %1, %2, %3" : "=v"(m2) : "v"(sA), "v"(ps1), "v"(lAs)); \
        float fu, fl, fd;                                                      \
        asm("v_exp_f32 %0, %1" : "=v"(fu) : "v"(m2 - sA));                     \
        asm("v_exp_f32 %0, %1" : "=v"(fl) : "v"(m2 - ps1));                    \
        asm("v_exp_f32 %0, %1" : "=v"(fd) : "v"(m2 - lAs));                    \
        float qB = __builtin_fmaf(qA, fu, __builtin_fmaf(pq1, fl, lAq * fd));  \
        float sB = cc.y + m2;                                                  \
        ps0 = sA; pq0 = qA; ps1 = sB; pq1 = qB;                                \
    }                                                                          \
    float shs_ = __shfl_up(ps1, 1);                                            \
    float shq_ = __shfl_up(pq1, 1);                                            \
    nbp_s = nbc_s; nbp_q = nbc_q;                                              \
    nbc_s = shs_;  nbc_q = shq_;                                               \
    if (l == 63) bsq[SW][w] = f32x2{ps1, pq1};                                 \
    LOADP(REG, s_ + RING - p);                                                 \
} while (0)

#define RENORM(S, Q) do {                                                      \
    int e_ = (__float_as_int(Q) >> 23) - 127;                                  \
    Q = __int_as_float(__float_as_int(Q) - (e_ << 23));                        \
    S = S - (float)e_;                                                         \
} while (0)

    for (int it = 0; it < 128; ++it) {
        int s0 = it * 6;
        STEP(r0, s0 + 0, 0, 2, 1);
        STEP(r1, s0 + 1, 1, 0, 2);
        STEP(r2, s0 + 2, 2, 1, 0);
        STEP(r3, s0 + 3, 0, 2, 1);
        STEP(r4, s0 + 4, 1, 0, 2);
        STEP(r5, s0 + 5, 2, 1, 0);
        RENORM(ps0, pq0);
        RENORM(ps1, pq1);
    }

    if (p == 255) {   // cell (511, 511): resolve once
        float lg;
        asm("v_log_f32 %0, %1" : "=v"(lg) : "v"(pq1));
        part[b] = (ps1 - lg) * LN2F;
    }
#undef STEP
#undef LOADP
#undef RENORM
}

// ---------------------------------------------------------------------------
// Kernel 4: one-wave deterministic reduction. out = sum_b(R_b) / (B * N)
// ---------------------------------------------------------------------------
__global__ __launch_bounds__(64) void reduce_kernel(const float* __restrict__ part,
                                                    float* __restrict__ out) {
    int l = threadIdx.x;
    float v = part[l];
    #pragma unroll
    for (int m = 32; m >= 1; m >>= 1) v += __shfl_xor(v, m, 64);
    if (l == 0) out[0] = v / (float)(BATCH * NN);
}

// ---------------------------------------------------------------------------
extern "C" void kernel_launch(void* const* d_in, const int* in_sizes, int n_in,
                              void* d_out, int out_size, void* d_ws, size_t ws_size,
                              hipStream_t stream) {
    const float* X = (const float*)d_in[0];
    const float* Y = (const float*)d_in[1];
    float* out = (float*)d_out;

    char* ws = (char*)d_ws;
    float* CT   = (float*)ws;                                   // 64 MB
    float* x2   = (float*)(ws + (size_t)BATCH * NN * MM * 4);   // 128 KB
    float* y2   = x2 + BATCH * NN;                              // 128 KB
    float* part = y2 + BATCH * MM;                              // 256 B

    sqnorm_kernel<<<(BATCH * (NN + MM)) / 4, 256, 0, stream>>>(X, Y, x2, y2);

    dim3 g(MM / TM, NN / TM, BATCH);
    cost_kernel<<<g, 256, 0, stream>>>(X, Y, x2, y2, CT);

    sdtw_kernel<<<BATCH, 256, 0, stream>>>(CT, part);

    reduce_kernel<<<1, 64, 0, stream>>>(part, out);
}